// Round 13
// baseline (128.192 us; speedup 1.0000x reference)
//
#include <hip/hip_runtime.h>

#define N_IN   128
#define LAYERS 6
#define N_H    320
#define DEG    32
#define N_OUT  18
#define N_TOTAL (N_IN + LAYERS * N_H)       // 2048
#define BB     8                            // batch elements per block
#define N_HID_UNITS (LAYERS * N_H)          // 1920

typedef _Float16 half2_t __attribute__((ext_vector_type(2)));
typedef _Float16 half8_t __attribute__((ext_vector_type(8)));

#if __has_builtin(__builtin_amdgcn_fdot2)
#define FDOT2(a, b, c) __builtin_amdgcn_fdot2((a), (b), (c), false)
#else
__device__ __forceinline__ float fdot2_sw(half2_t a, half2_t b, float c) {
    return c + (float)a[0] * (float)b[0] + (float)a[1] * (float)b[1];
}
#define FDOT2(a, b, c) fdot2_sw((a), (b), (c))
#endif

// f32x2 -> f16x2 pack (v_cvt_pkrtz_f16_f32); bit_cast because the builtin
// returns __fp16x2 while our vector typedef is _Float16x2 (same bits).
__device__ __forceinline__ half2_t pk_f16(float a, float b) {
    return __builtin_bit_cast(half2_t, __builtin_amdgcn_cvt_pkrtz(a, b));
}

__device__ __forceinline__ float fast_tanh(float x) {
    float e = __expf(2.0f * x);
    return 1.0f - 2.0f * __builtin_amdgcn_rcpf(e + 1.0f);
}

// ---------------------------------------------------------------------------
// Single-kernel version: the pack kernel is gone. The ledger across R1-R11
// shows bench = policy + ~52 us fixed harness overhead + ~6-7 us per extra
// dispatch; the pack rewrite (R11) was null because pack EXECUTION was tiny —
// the second launch itself was the cost. So the policy kernel now consumes
// hid_src/hid_w raw: +8 L2-hot dwordx4 per unit-layer and ~3 VALU/tap-pair
// (shift + v_cvt_pkrtz), riding under the LDS-pipe roofline.
//
// Roofline evidence (R5/R7/R8/R9): random wave64 ds_read_b128 costs ~26 cyc
// FIXED (crossbar service, not conflicts): conflict cuts of -15%/-27% and
// explicit pipelining all produced ZERO time change; read-count halving
// (R3->R5) halved time exactly. 992K wave reads x 26 cyc / 256 CU / 2.4 GHz
// = 42.1 us model vs 42.7-43.5 us measured.
// ---------------------------------------------------------------------------

// One tap-pair from raw tables: two random ds_read_b128 (each serving all 8
// batch elems), weight pair converted f32->f16x2 in one v_cvt_pkrtz, batch
// transposition via v_perm, 2 MACs/instr via v_dot2_f32_f16.
// All named scalars — nothing can fall to scratch (R4 lesson).
#define DOT_RAW(I0, I1, W0, W1) do {                                       \
    uint4 _g0 = *(const uint4*)(sA + ((unsigned)(I0) << 4));               \
    uint4 _g1 = *(const uint4*)(sA + ((unsigned)(I1) << 4));               \
    half2_t _wp = pk_f16((W0), (W1));                                      \
    unsigned _p0 = __builtin_amdgcn_perm(_g1.x, _g0.x, 0x05040100u);       \
    unsigned _p1 = __builtin_amdgcn_perm(_g1.x, _g0.x, 0x07060302u);       \
    unsigned _p2 = __builtin_amdgcn_perm(_g1.y, _g0.y, 0x05040100u);       \
    unsigned _p3 = __builtin_amdgcn_perm(_g1.y, _g0.y, 0x07060302u);       \
    unsigned _p4 = __builtin_amdgcn_perm(_g1.z, _g0.z, 0x05040100u);       \
    unsigned _p5 = __builtin_amdgcn_perm(_g1.z, _g0.z, 0x07060302u);       \
    unsigned _p6 = __builtin_amdgcn_perm(_g1.w, _g0.w, 0x05040100u);       \
    unsigned _p7 = __builtin_amdgcn_perm(_g1.w, _g0.w, 0x07060302u);       \
    acc0 = FDOT2(__builtin_bit_cast(half2_t, _p0), _wp, acc0);             \
    acc1 = FDOT2(__builtin_bit_cast(half2_t, _p1), _wp, acc1);             \
    acc2 = FDOT2(__builtin_bit_cast(half2_t, _p2), _wp, acc2);             \
    acc3 = FDOT2(__builtin_bit_cast(half2_t, _p3), _wp, acc3);             \
    acc4 = FDOT2(__builtin_bit_cast(half2_t, _p4), _wp, acc4);             \
    acc5 = FDOT2(__builtin_bit_cast(half2_t, _p5), _wp, acc5);             \
    acc6 = FDOT2(__builtin_bit_cast(half2_t, _p6), _wp, acc6);             \
    acc7 = FDOT2(__builtin_bit_cast(half2_t, _p7), _wp, acc7);             \
} while (0)

// 32 taps of one unit from raw src/w rows (16-B-aligned; L2-hot, identical
// across all 2048 blocks). Loads issued up front; compiler staggers vmcnt.
#define GATHER_UNIT_RAW(SRCROW, WROW) do {                                 \
    const int4*   _s4 = (const int4*)(SRCROW);                             \
    const float4* _w4 = (const float4*)(WROW);                             \
    int4   _s0 = _s4[0], _s1 = _s4[1], _s2 = _s4[2], _s3 = _s4[3];         \
    int4   _s4v = _s4[4], _s5 = _s4[5], _s6 = _s4[6], _s7 = _s4[7];        \
    float4 _v0 = _w4[0], _v1 = _w4[1], _v2 = _w4[2], _v3 = _w4[3];         \
    float4 _v4 = _w4[4], _v5 = _w4[5], _v6 = _w4[6], _v7 = _w4[7];         \
    DOT_RAW(_s0.x, _s0.y, _v0.x, _v0.y); DOT_RAW(_s0.z, _s0.w, _v0.z, _v0.w); \
    DOT_RAW(_s1.x, _s1.y, _v1.x, _v1.y); DOT_RAW(_s1.z, _s1.w, _v1.z, _v1.w); \
    DOT_RAW(_s2.x, _s2.y, _v2.x, _v2.y); DOT_RAW(_s2.z, _s2.w, _v2.z, _v2.w); \
    DOT_RAW(_s3.x, _s3.y, _v3.x, _v3.y); DOT_RAW(_s3.z, _s3.w, _v3.z, _v3.w); \
    DOT_RAW(_s4v.x, _s4v.y, _v4.x, _v4.y); DOT_RAW(_s4v.z, _s4v.w, _v4.z, _v4.w); \
    DOT_RAW(_s5.x, _s5.y, _v5.x, _v5.y); DOT_RAW(_s5.z, _s5.w, _v5.z, _v5.w); \
    DOT_RAW(_s6.x, _s6.y, _v6.x, _v6.y); DOT_RAW(_s6.z, _s6.w, _v6.z, _v6.w); \
    DOT_RAW(_s7.x, _s7.y, _v7.x, _v7.y); DOT_RAW(_s7.z, _s7.w, _v7.z, _v7.w); \
} while (0)

__global__ __launch_bounds__(N_H, 5) void policy_kernel(
    const float* __restrict__ obs,      // [B][N_IN]
    const int*   __restrict__ hid_src,  // [L][N_H][DEG]
    const float* __restrict__ hid_w,    // [L][N_H][DEG]
    const float* __restrict__ hid_b,    // [L][N_H]
    const int*   __restrict__ out_src,  // [N_OUT][DEG]
    const float* __restrict__ out_w,    // [N_OUT][DEG]
    const float* __restrict__ out_b,    // [N_OUT]
    float*       __restrict__ out)      // [B][N_OUT]
{
    // acts row r = 8 x f16 (one per batch elem) = 16 B -> one ds_read_b128/gather
    __shared__ alignas(16) unsigned char sA[N_TOTAL * 16];   // 32 KB -> 5 blocks/CU

    const int tid = threadIdx.x;
    const int b0  = blockIdx.x * BB;
    const int n   = tid;

    if (tid < N_IN) {
        half8_t hv;
        #pragma unroll
        for (int j = 0; j < BB; ++j) hv[j] = (_Float16)obs[(b0 + j) * N_IN + tid];
        *(half8_t*)(sA + tid * 16) = hv;
    }
    __syncthreads();

    for (int l = 0; l < LAYERS; ++l) {
        float acc0 = 0.f, acc1 = 0.f, acc2 = 0.f, acc3 = 0.f;
        float acc4 = 0.f, acc5 = 0.f, acc6 = 0.f, acc7 = 0.f;
        const int unit = l * N_H + n;
        GATHER_UNIT_RAW(hid_src + unit * DEG, hid_w + unit * DEG);

        float bias = hid_b[unit];
        half8_t hv;
        hv[0] = (_Float16)fast_tanh(acc0 + bias);
        hv[1] = (_Float16)fast_tanh(acc1 + bias);
        hv[2] = (_Float16)fast_tanh(acc2 + bias);
        hv[3] = (_Float16)fast_tanh(acc3 + bias);
        hv[4] = (_Float16)fast_tanh(acc4 + bias);
        hv[5] = (_Float16)fast_tanh(acc5 + bias);
        hv[6] = (_Float16)fast_tanh(acc6 + bias);
        hv[7] = (_Float16)fast_tanh(acc7 + bias);
        // this layer writes rows it never reads; one barrier per layer suffices
        *(half8_t*)(sA + (N_IN + unit) * 16) = hv;
        __syncthreads();
    }

    if (n < N_OUT) {
        float acc0 = 0.f, acc1 = 0.f, acc2 = 0.f, acc3 = 0.f;
        float acc4 = 0.f, acc5 = 0.f, acc6 = 0.f, acc7 = 0.f;
        GATHER_UNIT_RAW(out_src + n * DEG, out_w + n * DEG);
        float bias = out_b[n];
        out[(b0 + 0) * N_OUT + n] = fast_tanh(acc0 + bias);
        out[(b0 + 1) * N_OUT + n] = fast_tanh(acc1 + bias);
        out[(b0 + 2) * N_OUT + n] = fast_tanh(acc2 + bias);
        out[(b0 + 3) * N_OUT + n] = fast_tanh(acc3 + bias);
        out[(b0 + 4) * N_OUT + n] = fast_tanh(acc4 + bias);
        out[(b0 + 5) * N_OUT + n] = fast_tanh(acc5 + bias);
        out[(b0 + 6) * N_OUT + n] = fast_tanh(acc6 + bias);
        out[(b0 + 7) * N_OUT + n] = fast_tanh(acc7 + bias);
    }
}

extern "C" void kernel_launch(void* const* d_in, const int* in_sizes, int n_in,
                              void* d_out, int out_size, void* d_ws, size_t ws_size,
                              hipStream_t stream) {
    const float* obs     = (const float*)d_in[0];
    const int*   hid_src = (const int*)  d_in[1];
    const float* hid_w   = (const float*)d_in[2];
    const float* hid_b   = (const float*)d_in[3];
    const int*   out_src = (const int*)  d_in[4];
    const float* out_w   = (const float*)d_in[5];
    const float* out_b   = (const float*)d_in[6];
    float* out = (float*)d_out;

    const int batch = in_sizes[0] / N_IN;   // 8192
    policy_kernel<<<batch / BB, N_H, 0, stream>>>(
        obs, hid_src, hid_w, hid_b, out_src, out_w, out_b, out);
}

// Round 14
// 102.488 us; speedup vs baseline: 1.2508x; 1.2508x over previous
//
#include <hip/hip_runtime.h>

#define N_IN   128
#define LAYERS 6
#define N_H    320
#define DEG    32
#define N_OUT  18
#define N_TOTAL (N_IN + LAYERS * N_H)       // 2048
#define BB     8                            // batch elements per block
#define N_HID_UNITS (LAYERS * N_H)          // 1920
#define N_UNITS (N_HID_UNITS + N_OUT)       // 1938
#define N_PAIRS (N_UNITS * 16)              // 31008 tap-pairs

typedef _Float16 half2_t __attribute__((ext_vector_type(2)));
typedef _Float16 half8_t __attribute__((ext_vector_type(8)));

#if __has_builtin(__builtin_amdgcn_fdot2)
#define FDOT2(a, b, c) __builtin_amdgcn_fdot2((a), (b), (c), false)
#else
__device__ __forceinline__ float fdot2_sw(half2_t a, half2_t b, float c) {
    return c + (float)a[0] * (float)b[0] + (float)a[1] * (float)b[1];
}
#define FDOT2(a, b, c) fdot2_sw((a), (b), (c))
#endif

__device__ __forceinline__ float fast_tanh(float x) {
    float e = __expf(2.0f * x);
    return 1.0f - 2.0f * __builtin_amdgcn_rcpf(e + 1.0f);
}

// fused table per unit (32 dwords): [0..15] = offset pairs (idx0*16 | idx1*16<<16),
//                                   [16..31] = weight half2 pairs.
// One thread per tap-pair, coalesced int2/float2 loads.
// KEPT AS A SEPARATE KERNEL deliberately: R13 fused table consumption into the
// policy kernel (raw src/w reads) and regressed policy 43->70 us — 16 dwordx4
// per unit-layer can't stay live at VGPR=40, so global latency serializes.
// The ~7 us second dispatch is the cheaper alternative.
__global__ __launch_bounds__(256) void pack_kernel(
    const int* __restrict__ hid_src, const float* __restrict__ hid_w,
    const int* __restrict__ out_src, const float* __restrict__ out_w,
    unsigned int* __restrict__ fused)
{
    int t = blockIdx.x * 256 + threadIdx.x;
    if (t >= N_PAIRS) return;
    int u = t >> 4;          // unit
    int q = t & 15;          // tap-pair within unit
    int e = u * DEG + 2 * q; // element index in the hid tables

    int2   s;
    float2 w;
    if (u < N_HID_UNITS) {
        s = *(const int2*)  (hid_src + e);
        w = *(const float2*)(hid_w   + e);
    } else {
        int eo = (u - N_HID_UNITS) * DEG + 2 * q;
        s = *(const int2*)  (out_src + eo);
        w = *(const float2*)(out_w   + eo);
    }
    unsigned int* dst = fused + u * 32;
    dst[q] = ((unsigned)s.x << 4) | ((unsigned)s.y << 20);   // byte offsets, 16B rows
    half2_t wp;
    wp[0] = (_Float16)w.x;
    wp[1] = (_Float16)w.y;
    dst[16 + q] = __builtin_bit_cast(unsigned int, wp);
}

// ---- gather-dot: one random ds_read_b128 serves 8 batch elems -------------
// ROOFLINE NOTE (R5/R7/R8/R9/R13 evidence): random wave64 ds_read_b128 costs
// ~26 cyc FIXED (crossbar service, not conflicts). Conflict cuts of -15%/-27%
// (R7/R9), explicit pipelining (R8), and pack parallelization (R11) all gave
// ZERO time change; read-count halving (R3->R5) halved time exactly.
// 992K wave reads x 26 cyc / 256 CU / 2.4 GHz = 42.1 us model vs 42.7-43.5
// measured. Read count is floored: b128 is the widest DS access; 8 f16
// batch/row is the widest row within the accuracy budget.
#define LOADP(OD, G0, G1) do {                                             \
    unsigned _o0 = (OD) & 0xffffu;                                         \
    unsigned _o1 = (OD) >> 16;                                             \
    G0 = *(const uint4*)(sA + _o0);                                        \
    G1 = *(const uint4*)(sA + _o1);                                        \
} while (0)

#define CONSUME(G0, G1, WD) do {                                           \
    half2_t _wp = __builtin_bit_cast(half2_t, (WD));                       \
    unsigned _p0 = __builtin_amdgcn_perm(G1.x, G0.x, 0x05040100u);         \
    unsigned _p1 = __builtin_amdgcn_perm(G1.x, G0.x, 0x07060302u);         \
    unsigned _p2 = __builtin_amdgcn_perm(G1.y, G0.y, 0x05040100u);         \
    unsigned _p3 = __builtin_amdgcn_perm(G1.y, G0.y, 0x07060302u);         \
    unsigned _p4 = __builtin_amdgcn_perm(G1.z, G0.z, 0x05040100u);         \
    unsigned _p5 = __builtin_amdgcn_perm(G1.z, G0.z, 0x07060302u);         \
    unsigned _p6 = __builtin_amdgcn_perm(G1.w, G0.w, 0x05040100u);         \
    unsigned _p7 = __builtin_amdgcn_perm(G1.w, G0.w, 0x07060302u);         \
    acc0 = FDOT2(__builtin_bit_cast(half2_t, _p0), _wp, acc0);             \
    acc1 = FDOT2(__builtin_bit_cast(half2_t, _p1), _wp, acc1);             \
    acc2 = FDOT2(__builtin_bit_cast(half2_t, _p2), _wp, acc2);             \
    acc3 = FDOT2(__builtin_bit_cast(half2_t, _p3), _wp, acc3);             \
    acc4 = FDOT2(__builtin_bit_cast(half2_t, _p4), _wp, acc4);             \
    acc5 = FDOT2(__builtin_bit_cast(half2_t, _p5), _wp, acc5);             \
    acc6 = FDOT2(__builtin_bit_cast(half2_t, _p6), _wp, acc6);             \
    acc7 = FDOT2(__builtin_bit_cast(half2_t, _p7), _wp, acc7);             \
} while (0)

// 16 tap-pairs, register double-buffered (neutral vs plain, kept from R8).
#define GATHER_UNIT(BASE) do {                                             \
    const uint4* _t = ftab + (BASE);                                       \
    uint4 _fo0 = _t[0], _fo1 = _t[1], _fo2 = _t[2], _fo3 = _t[3];          \
    uint4 _fw0 = _t[4], _fw1 = _t[5], _fw2 = _t[6], _fw3 = _t[7];          \
    uint4 ga0, ga1, gb0, gb1;                                              \
    LOADP(_fo0.x, ga0, ga1);                                               \
    LOADP(_fo0.y, gb0, gb1); CONSUME(ga0, ga1, _fw0.x);                    \
    LOADP(_fo0.z, ga0, ga1); CONSUME(gb0, gb1, _fw0.y);                    \
    LOADP(_fo0.w, gb0, gb1); CONSUME(ga0, ga1, _fw0.z);                    \
    LOADP(_fo1.x, ga0, ga1); CONSUME(gb0, gb1, _fw0.w);                    \
    LOADP(_fo1.y, gb0, gb1); CONSUME(ga0, ga1, _fw1.x);                    \
    LOADP(_fo1.z, ga0, ga1); CONSUME(gb0, gb1, _fw1.y);                    \
    LOADP(_fo1.w, gb0, gb1); CONSUME(ga0, ga1, _fw1.z);                    \
    LOADP(_fo2.x, ga0, ga1); CONSUME(gb0, gb1, _fw1.w);                    \
    LOADP(_fo2.y, gb0, gb1); CONSUME(ga0, ga1, _fw2.x);                    \
    LOADP(_fo2.z, ga0, ga1); CONSUME(gb0, gb1, _fw2.y);                    \
    LOADP(_fo2.w, gb0, gb1); CONSUME(ga0, ga1, _fw2.z);                    \
    LOADP(_fo3.x, ga0, ga1); CONSUME(gb0, gb1, _fw2.w);                    \
    LOADP(_fo3.y, gb0, gb1); CONSUME(ga0, ga1, _fw3.x);                    \
    LOADP(_fo3.z, ga0, ga1); CONSUME(gb0, gb1, _fw3.y);                    \
    LOADP(_fo3.w, gb0, gb1); CONSUME(ga0, ga1, _fw3.z);                    \
    CONSUME(gb0, gb1, _fw3.w);                                             \
} while (0)

__global__ __launch_bounds__(N_H, 5) void policy_kernel(
    const float* __restrict__ obs,       // [B][N_IN]
    const uint4* __restrict__ ftab,      // [N_UNITS][8] fused offsets+weights
    const float* __restrict__ hid_b,     // [L][N_H]
    const float* __restrict__ out_b,     // [N_OUT]
    float*       __restrict__ out)       // [B][N_OUT]
{
    // acts row r = 8 x f16 (one per batch elem) = 16 B -> one ds_read_b128/gather
    __shared__ alignas(16) unsigned char sA[N_TOTAL * 16];   // 32 KB -> 5 blocks/CU

    const int tid = threadIdx.x;
    const int b0  = blockIdx.x * BB;
    const int n   = tid;

    if (tid < N_IN) {
        half8_t hv;
        #pragma unroll
        for (int j = 0; j < BB; ++j) hv[j] = (_Float16)obs[(b0 + j) * N_IN + tid];
        *(half8_t*)(sA + tid * 16) = hv;
    }
    __syncthreads();

    for (int l = 0; l < LAYERS; ++l) {
        float acc0 = 0.f, acc1 = 0.f, acc2 = 0.f, acc3 = 0.f;
        float acc4 = 0.f, acc5 = 0.f, acc6 = 0.f, acc7 = 0.f;
        GATHER_UNIT((l * N_H + n) * 8);

        float bias = hid_b[l * N_H + n];
        half8_t hv;
        hv[0] = (_Float16)fast_tanh(acc0 + bias);
        hv[1] = (_Float16)fast_tanh(acc1 + bias);
        hv[2] = (_Float16)fast_tanh(acc2 + bias);
        hv[3] = (_Float16)fast_tanh(acc3 + bias);
        hv[4] = (_Float16)fast_tanh(acc4 + bias);
        hv[5] = (_Float16)fast_tanh(acc5 + bias);
        hv[6] = (_Float16)fast_tanh(acc6 + bias);
        hv[7] = (_Float16)fast_tanh(acc7 + bias);
        // this layer writes rows it never reads; one barrier per layer suffices
        *(half8_t*)(sA + (N_IN + l * N_H + n) * 16) = hv;
        __syncthreads();
    }

    if (n < N_OUT) {
        float acc0 = 0.f, acc1 = 0.f, acc2 = 0.f, acc3 = 0.f;
        float acc4 = 0.f, acc5 = 0.f, acc6 = 0.f, acc7 = 0.f;
        GATHER_UNIT((N_HID_UNITS + n) * 8);
        float bias = out_b[n];
        out[(b0 + 0) * N_OUT + n] = fast_tanh(acc0 + bias);
        out[(b0 + 1) * N_OUT + n] = fast_tanh(acc1 + bias);
        out[(b0 + 2) * N_OUT + n] = fast_tanh(acc2 + bias);
        out[(b0 + 3) * N_OUT + n] = fast_tanh(acc3 + bias);
        out[(b0 + 4) * N_OUT + n] = fast_tanh(acc4 + bias);
        out[(b0 + 5) * N_OUT + n] = fast_tanh(acc5 + bias);
        out[(b0 + 6) * N_OUT + n] = fast_tanh(acc6 + bias);
        out[(b0 + 7) * N_OUT + n] = fast_tanh(acc7 + bias);
    }
}

extern "C" void kernel_launch(void* const* d_in, const int* in_sizes, int n_in,
                              void* d_out, int out_size, void* d_ws, size_t ws_size,
                              hipStream_t stream) {
    const float* obs     = (const float*)d_in[0];
    const int*   hid_src = (const int*)  d_in[1];
    const float* hid_w   = (const float*)d_in[2];
    const float* hid_b   = (const float*)d_in[3];
    const int*   out_src = (const int*)  d_in[4];
    const float* out_w   = (const float*)d_in[5];
    const float* out_b   = (const float*)d_in[6];
    float* out = (float*)d_out;
    unsigned int* fused = (unsigned int*)d_ws;   // 1938*32*4 = 248 KB

    const int batch = in_sizes[0] / N_IN;   // 8192

    pack_kernel<<<(N_PAIRS + 255) / 256, 256, 0, stream>>>(
        hid_src, hid_w, out_src, out_w, fused);
    policy_kernel<<<batch / BB, N_H, 0, stream>>>(
        obs, (const uint4*)fused, hid_b, out_b, out);
}